// Round 8
// baseline (208.397 us; speedup 1.0000x reference)
//
#include <hip/hip_runtime.h>
#include <stdint.h>

#define N 8192
#define NCLS 80
#define NWD 128             // keep-mask words (8192 bits)
#define PAIR_CAP (1 << 20)  // 1M edges (4 MB); expected E ~ 2K
#define K2_BLOCKS 2112      // sum_{ti<32} (128 - 4*ti) upper-trapezoid tiles

// ---------------- K1: argmax + precompute + optimistic outputs ----------
// 8 threads/box. Writes corners/meta in ORIGINAL index order (coalesced, no
// atomics) and outputs as if keep==valid; k_main's tail zeroes the few
// suppressed boxes. Also zeroes k_main's counters (consumed next dispatch).
__global__ void __launch_bounds__(256) k_prep(
    const float* __restrict__ box, const float* __restrict__ conf,
    const float* __restrict__ logits,
    float4* __restrict__ sb, float4* __restrict__ sm,
    int* __restrict__ cnt, float* __restrict__ out)
{
#pragma clang fp contract(off)
    int gid = blockIdx.x * 256 + threadIdx.x;      // 0..65535
    if (gid == 0) { cnt[1] = 0; cnt[2] = 0; }      // paircnt, done
    int i = gid >> 3, s = gid & 7;
    const float4* lp = (const float4*)(logits + (size_t)i * NCLS);
    float best = -INFINITY; int bi = 0;
#pragma unroll
    for (int k2 = 0; k2 < 3; ++k2) {
        int c4 = s + 8 * k2;                       // 20 float4 chunks / 8 lanes
        if (c4 < 20) {
            float4 v = lp[c4]; int b = c4 * 4;
            if (v.x > best) { best = v.x; bi = b; }
            if (v.y > best) { best = v.y; bi = b + 1; }
            if (v.z > best) { best = v.z; bi = b + 2; }
            if (v.w > best) { best = v.w; bi = b + 3; }
        }
    }
    // 8-lane butterfly; ties -> lowest index (jnp first-max)
#pragma unroll
    for (int off = 1; off < 8; off <<= 1) {
        float ob = __shfl_xor(best, off, 8);
        int   oi = __shfl_xor(bi, off, 8);
        if (ob > best || (ob == best && oi < bi)) { best = ob; bi = oi; }
    }
    if (s == 0) {
        float c = conf[i];
        float m = (c > 0.5f) ? 1.0f : 0.0f;
        float4 b = ((const float4*)box)[i];        // x, y, w, h
        float hw = b.z * 0.5f, hh = b.w * 0.5f;    // == w/2 exactly
        sb[i] = make_float4(b.x - hw, b.y - hh, b.x + hw, b.y + hh);
        sm[i] = make_float4(b.z * b.w, c, (float)bi, m);
        out[i * 5 + 0] = b.x * m;                  // x*1.0f == x bitwise
        out[i * 5 + 1] = b.y * m;
        out[i * 5 + 2] = b.z * m;
        out[i * 5 + 3] = b.w * m;
        out[i * 5 + 4] = c * m;
        out[5 * N + i] = (float)bi;
        out[6 * N + i] = m;
    }
}

// ---------------- K2: pairs (branch-free) + last-block tail -------------
// 256-row x 64-col tiles over the upper trapezoid of 8192^2 (2112 blocks,
// ~8/CU). Validity folded into class sentinels (invalid never matches).
// Candidate pass: 2 LDS broadcasts + ~12 VALU per iter, no branch/divide;
// rare candidates get the exact __fdiv_rn IoU + directed-edge emit.
// Last finishing block: Jacobi fixpoint + sparse output correction.
__global__ void __launch_bounds__(256) k_main(
    const float4* __restrict__ sb, const float4* __restrict__ sm,
    int* __restrict__ cnt,              // [1]=paircnt [2]=done
    unsigned int* __restrict__ pairs,
    const float* __restrict__ conf, float* __restrict__ out)
{
#pragma clang fp contract(off)
    __shared__ float4 cb[64];
    __shared__ float  carea[64], cconf[64];
    __shared__ int    ccls[64];
    int tid = threadIdx.x;

    // decode blockIdx.x -> (ti, tj): row-tile ti (256 rows), col-tile tj (64
    // cols), tj in [4*ti, 128)
    int bres = blockIdx.x, ti = 0;
    while (bres >= 128 - 4 * ti) { bres -= 128 - 4 * ti; ++ti; }
    int tj = 4 * ti + bres;
    int rbase = ti << 8, cbase = tj << 6;

    if (tid < 64) {
        int c = cbase + tid;
        float4 m4 = sm[c];
        cb[tid] = sb[c];
        carea[tid] = m4.x;
        cconf[tid] = m4.y;
        // invalid -> unique sentinel: never equals any valid rcls or -1
        ccls[tid] = (m4.w != 0.0f) ? (int)m4.z : (0x10000 + c);
    }
    __syncthreads();

    int r = rbase + tid;
    float4 rb = sb[r];
    float4 rm = sm[r];
    float rar = rm.x, rconf = rm.y;
    int rcls = (rm.w != 0.0f) ? (int)rm.z : -1;

    unsigned long long cand = 0ULL;
#pragma unroll 8
    for (int k = 0; k < 64; ++k) {                 // branch-free, divide-free
        int c = cbase + k;
        float4 c4 = cb[k];
        float iw = fminf(rb.z, c4.z) - fmaxf(rb.x, c4.x);
        float ih = fminf(rb.w, c4.w) - fmaxf(rb.y, c4.y);
        bool pc = (ccls[k] == rcls) & (c > r) & (iw > 0.0f) & (ih > 0.0f);
        cand |= ((unsigned long long)pc) << k;
    }
    while (cand) {                                 // rare (~0.3% of pairs)
        int k = __builtin_ctzll(cand);
        cand &= cand - 1;
        float4 c4 = cb[k];
        // exact float32 op order of the reference:
        float iw = fminf(rb.z, c4.z) - fmaxf(rb.x, c4.x);
        iw = fmaxf(iw, 0.0f);
        float ih = fminf(rb.w, c4.w) - fmaxf(rb.y, c4.y);
        ih = fmaxf(ih, 0.0f);
        float inter = iw * ih;
        float uni = rar + carea[k] - inter;
        float iou = __fdiv_rn(inter, uni);         // IEEE divide
        if (iou > 0.5f) {
            // earlier in (conf desc, idx asc) suppresses later; r < c always
            unsigned int c = (unsigned)(cbase + k);
            unsigned int e = (rconf >= cconf[k])
                ? (((unsigned)r << 13) | c) : ((c << 13) | (unsigned)r);
            int idx = atomicAdd(&cnt[1], 1);
            if (idx < PAIR_CAP) pairs[idx] = e;
        }
    }

    // ---- completion protocol: last block does the serial tail ----
    __shared__ int lastflag;
    __threadfence();                               // release pair writes
    __syncthreads();
    if (tid == 0) lastflag = (atomicAdd(&cnt[2], 1) == K2_BLOCKS - 1);
    __syncthreads();
    if (!lastflag) return;
    __threadfence();                               // acquire all pairs

    // ---- Jacobi fixpoint over sparse suppression DAG (LDS) ----
    // keep_{t+1}[v] = valid[v] & !exists edge u->v with keep_t[u]; edges
    // follow key order (DAG) => unique fixpoint == sequential greedy scan.
    __shared__ unsigned long long keep[NWD], sn[NWD], vmw[NWD];
    __shared__ int chg;
    int E = cnt[1]; if (E > PAIR_CAP) E = PAIR_CAP;
#pragma unroll
    for (int rr = 0; rr < 32; ++rr) {              // valid mask via ballot
        int i = rr * 256 + tid;
        unsigned long long bb = __ballot(conf[i] > 0.5f);
        if ((tid & 63) == 0) { vmw[i >> 6] = bb; keep[i >> 6] = bb; }
    }
    __syncthreads();
    for (int round = 0; round < 8192; ++round) {
        if (tid < NWD) sn[tid] = 0ULL;
        if (tid == 0) chg = 0;
        __syncthreads();
        for (int e = tid; e < E; e += 256) {
            unsigned int p = pairs[e];
            int u = p >> 13, v = p & 8191;
            if ((keep[u >> 6] >> (u & 63)) & 1ULL)
                atomicOr(&sn[v >> 6], 1ULL << (v & 63));
        }
        __syncthreads();
        if (tid < NWD) {
            unsigned long long nk = vmw[tid] & ~sn[tid];
            if (nk != keep[tid]) { keep[tid] = nk; chg = 1; }
        }
        __syncthreads();
        if (!chg) break;
    }

    // ---- sparse output correction: zero the suppressed boxes ----
    for (int rr = 0; rr < 32; ++rr) {
        int i = rr * 256 + tid;
        // suppressed = valid & ~keep  (keep is a subset of valid)
        if ((vmw[i >> 6] ^ keep[i >> 6]) >> (i & 63) & 1ULL) {
            out[i * 5 + 0] = 0.0f;
            out[i * 5 + 1] = 0.0f;
            out[i * 5 + 2] = 0.0f;
            out[i * 5 + 3] = 0.0f;
            out[i * 5 + 4] = 0.0f;
            out[6 * N + i] = 0.0f;
        }
    }
}

// ---------------- launch -------------------------------------------------
extern "C" void kernel_launch(void* const* d_in, const int* in_sizes, int n_in,
                              void* d_out, int out_size, void* d_ws, size_t ws_size,
                              hipStream_t stream) {
    const float* box    = (const float*)d_in[0];
    const float* conf   = (const float*)d_in[1];
    const float* logits = (const float*)d_in[2];
    float* out = (float*)d_out;

    char* ws = (char*)d_ws;
    float4* sb    = (float4*)(ws + 0);                    // 128 KB corners
    float4* sm    = (float4*)(ws + 131072);               // 128 KB area/conf/cls/valid
    int* cnt      = (int*)(ws + 262144);                  // counters
    unsigned int* pairs = (unsigned int*)(ws + 266240);   // 4 MB

    k_prep<<<256, 256, 0, stream>>>(box, conf, logits, sb, sm, cnt, out);
    k_main<<<K2_BLOCKS, 256, 0, stream>>>(sb, sm, cnt, pairs, conf, out);
}